// Round 1
// baseline (33.815 us; speedup 1.0000x reference)
//
#include <hip/hip_runtime.h>
#include <math.h>

#define WHVI_D 2048

// ---------------------------------------------------------------------------
// Kernel 1: u_perm[p] = (g_mu[i] + sqrt(softplus(g_rho[i])) * eps[i]) / 2048
// stored in the permuted ("T-layout") order the main kernel reads:
//   p = lane*32 + r'   with  lane = b*32 + m'
//   i = (m'>>2)*256 + b*128 + r'*4 + (m'&3)
// ---------------------------------------------------------------------------
__global__ __launch_bounds__(256) void whvi_uperm_kernel(
    const float* __restrict__ g_mu,
    const float* __restrict__ g_rho,
    const float* __restrict__ eps,
    float* __restrict__ u_perm)
{
    int p = blockIdx.x * 256 + threadIdx.x;
    if (p >= WHVI_D) return;
    int rp = p & 31;          // r'
    int mp = (p >> 5) & 31;   // m'
    int bb = (p >> 10) & 1;   // b
    int i  = ((mp >> 2) << 8) | (bb << 7) | (rp << 2) | (mp & 3);
    float rho = g_rho[i];
    // numerically stable softplus, matches jax.nn.softplus in f32
    float sp  = fmaxf(rho, 0.0f) + log1pf(expf(-fabsf(rho)));
    float u   = fmaf(sqrtf(sp), eps[i], g_mu[i]);
    u_perm[p] = u * (1.0f / 2048.0f);   // exact power-of-2 Hadamard norm (D^-1/2 twice)
}

// ---------------------------------------------------------------------------
// In-register butterfly over the 32-element register dimension, xor-mask M.
// Element with the M-bit clear gets a+b, the other a-b (Sylvester H2).
// All indices compile-time (full unroll) so v[] stays in VGPRs.
// ---------------------------------------------------------------------------
template <int M>
__device__ __forceinline__ void bfly_reg(float (&v)[32]) {
#pragma unroll
    for (int r = 0; r < 32; ++r) {
        if (!(r & M)) {
            float a = v[r], c = v[r ^ M];
            v[r]     = a + c;
            v[r ^ M] = a - c;
        }
    }
}

// Butterfly across lane-bit 5 (i-bit 7): partner = lane ^ 32.
__device__ __forceinline__ void bfly_lane32(float (&v)[32], int hi) {
#pragma unroll
    for (int r = 0; r < 32; ++r) {
        float p = __shfl_xor(v[r], 32, 64);
        v[r] = hi ? (p - v[r]) : (v[r] + p);
    }
}

// ---------------------------------------------------------------------------
// Main kernel: one wave per row.
// Layout P: reg r=j*4+c, lane L -> element i = j*256 + L*4 + c  (coalesced IO)
// Layout T (after transpose): lane (b,m'), reg r' -> i = (m'>>2)*256 + b*128 + r'*4 + (m'&3)
// FWHT = bits {0,1,8,9,10} in P-regs, bit 7 via lane-xor-32, bits {2..6} in T-regs.
// Transpose: per-wave 2 x 32x36 f32 LDS tile (144 B row stride: b128 writes
// spread over 8 bank-quads = floor; column b32 reads conflict-free).
// ---------------------------------------------------------------------------
__global__ __launch_bounds__(256, 4) void whvi_main_kernel(
    const float* __restrict__ x,
    const float* __restrict__ s1,
    const float* __restrict__ s2,
    const float* __restrict__ u_perm,
    float* __restrict__ out)
{
    __shared__ __align__(16) float lds[4][2][32][36];   // 36864 B / block

    const int tid  = threadIdx.x;
    const int wid  = tid >> 6;
    const int lane = tid & 63;
    const int b    = lane >> 5;
    const int m    = lane & 31;
    const long row = (long)blockIdx.x * 4 + wid;

    const float* __restrict__ xr   = x   + row * WHVI_D;
    float*       __restrict__ orow = out + row * WHVI_D;

    float v[32];

    // ---- load x, fold in s2 (layout P) ----
#pragma unroll
    for (int j = 0; j < 8; ++j) {
        const float4 xv = *reinterpret_cast<const float4*>(xr + j * 256 + lane * 4);
        const float4 sv = *reinterpret_cast<const float4*>(s2 + j * 256 + lane * 4);
        v[j * 4 + 0] = xv.x * sv.x;
        v[j * 4 + 1] = xv.y * sv.y;
        v[j * 4 + 2] = xv.z * sv.z;
        v[j * 4 + 3] = xv.w * sv.w;
    }

    float*       wrow = &lds[wid][0][0][0] + b * (32 * 36) + m * 36;
    const float* rcol = &lds[wid][0][0][0] + b * (32 * 36) + m;

    // ================= FWHT #1 =================
    bfly_reg<1>(v); bfly_reg<2>(v); bfly_reg<4>(v); bfly_reg<8>(v); bfly_reg<16>(v);
    bfly_lane32(v, b);
    // transpose P -> T (intra-wave, no block barrier needed)
#pragma unroll
    for (int q = 0; q < 8; ++q) {
        float4 t;
        t.x = v[4 * q + 0]; t.y = v[4 * q + 1]; t.z = v[4 * q + 2]; t.w = v[4 * q + 3];
        *reinterpret_cast<float4*>(wrow + 4 * q) = t;
    }
    asm volatile("s_waitcnt lgkmcnt(0)" ::: "memory");
#pragma unroll
    for (int r = 0; r < 32; ++r) v[r] = rcol[r * 36];
    bfly_reg<1>(v); bfly_reg<2>(v); bfly_reg<4>(v); bfly_reg<8>(v); bfly_reg<16>(v);

    // ---- elementwise u (permuted, L1-resident) ----
#pragma unroll
    for (int k = 0; k < 8; ++k) {
        const float4 uv = *reinterpret_cast<const float4*>(u_perm + lane * 32 + k * 4);
        v[k * 4 + 0] *= uv.x;
        v[k * 4 + 1] *= uv.y;
        v[k * 4 + 2] *= uv.z;
        v[k * 4 + 3] *= uv.w;
    }

    // ================= FWHT #2 =================
    bfly_reg<1>(v); bfly_reg<2>(v); bfly_reg<4>(v); bfly_reg<8>(v); bfly_reg<16>(v);
    bfly_lane32(v, b);
    asm volatile("s_waitcnt lgkmcnt(0)" ::: "memory");   // drain reads before buffer reuse
    // transpose T -> P (same operation)
#pragma unroll
    for (int q = 0; q < 8; ++q) {
        float4 t;
        t.x = v[4 * q + 0]; t.y = v[4 * q + 1]; t.z = v[4 * q + 2]; t.w = v[4 * q + 3];
        *reinterpret_cast<float4*>(wrow + 4 * q) = t;
    }
    asm volatile("s_waitcnt lgkmcnt(0)" ::: "memory");
#pragma unroll
    for (int r = 0; r < 32; ++r) v[r] = rcol[r * 36];
    bfly_reg<1>(v); bfly_reg<2>(v); bfly_reg<4>(v); bfly_reg<8>(v); bfly_reg<16>(v);

    // ---- fold in s1, store (layout P, coalesced) ----
#pragma unroll
    for (int j = 0; j < 8; ++j) {
        const float4 sv = *reinterpret_cast<const float4*>(s1 + j * 256 + lane * 4);
        float4 ov;
        ov.x = v[j * 4 + 0] * sv.x;
        ov.y = v[j * 4 + 1] * sv.y;
        ov.z = v[j * 4 + 2] * sv.z;
        ov.w = v[j * 4 + 3] * sv.w;
        *reinterpret_cast<float4*>(orow + j * 256 + lane * 4) = ov;
    }
}

extern "C" void kernel_launch(void* const* d_in, const int* in_sizes, int n_in,
                              void* d_out, int out_size, void* d_ws, size_t ws_size,
                              hipStream_t stream)
{
    const float* x     = (const float*)d_in[0];
    const float* s1    = (const float*)d_in[1];
    const float* s2    = (const float*)d_in[2];
    const float* g_mu  = (const float*)d_in[3];
    const float* g_rho = (const float*)d_in[4];
    const float* eps   = (const float*)d_in[5];
    // d_in[6] = H is unused: we apply the fast Walsh-Hadamard transform instead.

    float* u_perm = (float*)d_ws;      // 2048 floats = 8 KB scratch
    float* outp   = (float*)d_out;

    whvi_uperm_kernel<<<8, 256, 0, stream>>>(g_mu, g_rho, eps, u_perm);

    const int rows = out_size / WHVI_D;          // 8192
    whvi_main_kernel<<<rows / 4, 256, 0, stream>>>(x, s1, s2, u_perm, outp);
}

// Round 2
// 33.037 us; speedup vs baseline: 1.0235x; 1.0235x over previous
//
#include <hip/hip_runtime.h>
#include <math.h>

#define WHVI_D 2048

typedef int v2i __attribute__((ext_vector_type(2)));

// ---------------------------------------------------------------------------
// In-register butterfly over the 32-reg dimension, xor-mask M (i bits 0,1,8,9,10).
// ---------------------------------------------------------------------------
template <int M>
__device__ __forceinline__ void bfly_reg(float (&v)[32]) {
#pragma unroll
    for (int r = 0; r < 32; ++r) {
        if (!(r & M)) {
            float a = v[r], c = v[r ^ M];
            v[r]     = a + c;
            v[r ^ M] = a - c;
        }
    }
}

// ---------------------------------------------------------------------------
// Lane-xor butterfly via DPP (VALU pipe, no DS): p = v[lane^k]; v = sgn*v + p.
// sgn = +1 on lanes with the bit clear (gets a+b), -1 on set (gets a-b, since
// there p = partner a and v = b -> fma(-1, b, a) = a-b).
// CTRL: 0xB1 = quad_perm [1,0,3,2] (xor1), 0x4E = [2,3,0,1] (xor2),
//       0x128 = row_ror:8 (xor8 within 16-lane rows).
// ---------------------------------------------------------------------------
template <int CTRL>
__device__ __forceinline__ void bfly_dpp(float (&v)[32], float sgn) {
#pragma unroll
    for (int r = 0; r < 32; ++r) {
        int p = __builtin_amdgcn_mov_dpp(__float_as_int(v[r]), CTRL, 0xF, 0xF, false);
        v[r] = fmaf(sgn, v[r], __int_as_float(p));
    }
}

// Lane-xor-4 via ds_swizzle BitMode: offset = (4<<10)|(0<<5)|31 = 0x101F.
__device__ __forceinline__ void bfly_swz4(float (&v)[32], float sgn) {
#pragma unroll
    for (int r = 0; r < 32; ++r) {
        int p = __builtin_amdgcn_ds_swizzle(__float_as_int(v[r]), 0x101F);
        v[r] = fmaf(sgn, v[r], __int_as_float(p));
    }
}

// ---------------------------------------------------------------------------
// Lane-xor 16 / 32 via v_permlane16/32_swap_b32 pair trick (2 regs at a time):
//   swap(a,b): a1 = interleave(a_even_rows, b_even_rows), b1 = (a_odd, b_odd)
//   s = a1+b1, d = a1-b1; swap(s,d) -> exactly the butterfly results of a and b.
// 2 swaps + 1 add + 1 sub per reg pair, all on the VALU pipe.
// ---------------------------------------------------------------------------
template <bool IS32>
__device__ __forceinline__ void bfly_permlane(float (&v)[32]) {
#pragma unroll
    for (int r = 0; r < 32; r += 2) {
        int a = __float_as_int(v[r]), b = __float_as_int(v[r + 1]);
        v2i t;
        if constexpr (IS32) t = __builtin_amdgcn_permlane32_swap(a, b, false, false);
        else                t = __builtin_amdgcn_permlane16_swap(a, b, false, false);
        float s = __int_as_float(t.x) + __int_as_float(t.y);
        float d = __int_as_float(t.x) - __int_as_float(t.y);
        v2i w;
        if constexpr (IS32) w = __builtin_amdgcn_permlane32_swap(__float_as_int(s), __float_as_int(d), false, false);
        else                w = __builtin_amdgcn_permlane16_swap(__float_as_int(s), __float_as_int(d), false, false);
        v[r]     = __int_as_float(w.x);
        v[r + 1] = __int_as_float(w.y);
    }
}

// Full 2048-point FWHT, layout P: reg r=j*4+c, lane L -> i = j*256 + L*4 + c.
// reg bits {0,1,8,9,10}; lane bits 0..5 = i bits 2..7. Stages commute.
__device__ __forceinline__ void fwht(float (&v)[32], float sg1, float sg2,
                                     float sg4, float sg8) {
    bfly_reg<1>(v); bfly_reg<2>(v); bfly_reg<4>(v); bfly_reg<8>(v); bfly_reg<16>(v);
    bfly_dpp<0xB1>(v, sg1);    // i bit 2
    bfly_dpp<0x4E>(v, sg2);    // i bit 3
    bfly_swz4(v, sg4);         // i bit 4 (only DS-pipe stage)
    bfly_dpp<0x128>(v, sg8);   // i bit 5
    bfly_permlane<false>(v);   // i bit 6
    bfly_permlane<true>(v);    // i bit 7
}

// ---------------------------------------------------------------------------
// One wave per row, 8 rows per 512-thread block. No transposes, no barriers
// except the one u-broadcast sync. u computed per-block into LDS while the
// row's x-loads are in flight.
// ---------------------------------------------------------------------------
__global__ __launch_bounds__(512, 4) void whvi_main_kernel(
    const float* __restrict__ x,
    const float* __restrict__ s1,
    const float* __restrict__ s2,
    const float* __restrict__ g_mu,
    const float* __restrict__ g_rho,
    const float* __restrict__ eps,
    float* __restrict__ out)
{
    __shared__ __align__(16) float uS[WHVI_D];   // 8 KB

    const int  tid  = threadIdx.x;
    const int  wid  = tid >> 6;
    const int  lane = tid & 63;
    const long row  = (long)blockIdx.x * 8 + wid;

    const float* __restrict__ xr   = x   + row * WHVI_D;
    float*       __restrict__ orow = out + row * WHVI_D;

    // Issue the HBM x-stream first so it overlaps the transcendental u work.
    float4 xv[8];
#pragma unroll
    for (int j = 0; j < 8; ++j)
        xv[j] = *reinterpret_cast<const float4*>(xr + j * 256 + lane * 4);

    // u[i] = (g_mu + sqrt(softplus(g_rho)) * eps) / 2048, natural order.
#pragma unroll
    for (int k = 0; k < 4; ++k) {
        int   i  = k * 512 + tid;
        float r  = g_rho[i];
        float sp = fmaxf(r, 0.0f) + __logf(1.0f + __expf(-fabsf(r)));
        uS[i] = fmaf(sqrtf(sp), eps[i], g_mu[i]) * (1.0f / 2048.0f);
    }
    __syncthreads();

    const float sg1 = (lane & 1) ? -1.0f : 1.0f;
    const float sg2 = (lane & 2) ? -1.0f : 1.0f;
    const float sg4 = (lane & 4) ? -1.0f : 1.0f;
    const float sg8 = (lane & 8) ? -1.0f : 1.0f;

    // v = x * s2 (s2 is 8 KB, L1/L2-resident broadcast)
    float v[32];
#pragma unroll
    for (int j = 0; j < 8; ++j) {
        const float4 sv = *reinterpret_cast<const float4*>(s2 + j * 256 + lane * 4);
        v[j * 4 + 0] = xv[j].x * sv.x;
        v[j * 4 + 1] = xv[j].y * sv.y;
        v[j * 4 + 2] = xv[j].z * sv.z;
        v[j * 4 + 3] = xv[j].w * sv.w;
    }

    fwht(v, sg1, sg2, sg4, sg8);

    // elementwise u (LDS, conflict-free b128 pattern)
#pragma unroll
    for (int j = 0; j < 8; ++j) {
        const float4 uv = *reinterpret_cast<const float4*>(&uS[j * 256 + lane * 4]);
        v[j * 4 + 0] *= uv.x;
        v[j * 4 + 1] *= uv.y;
        v[j * 4 + 2] *= uv.z;
        v[j * 4 + 3] *= uv.w;
    }

    fwht(v, sg1, sg2, sg4, sg8);

    // fold in s1, coalesced float4 store
#pragma unroll
    for (int j = 0; j < 8; ++j) {
        const float4 sv = *reinterpret_cast<const float4*>(s1 + j * 256 + lane * 4);
        float4 ov;
        ov.x = v[j * 4 + 0] * sv.x;
        ov.y = v[j * 4 + 1] * sv.y;
        ov.z = v[j * 4 + 2] * sv.z;
        ov.w = v[j * 4 + 3] * sv.w;
        *reinterpret_cast<float4*>(orow + j * 256 + lane * 4) = ov;
    }
}

extern "C" void kernel_launch(void* const* d_in, const int* in_sizes, int n_in,
                              void* d_out, int out_size, void* d_ws, size_t ws_size,
                              hipStream_t stream)
{
    const float* x     = (const float*)d_in[0];
    const float* s1    = (const float*)d_in[1];
    const float* s2    = (const float*)d_in[2];
    const float* g_mu  = (const float*)d_in[3];
    const float* g_rho = (const float*)d_in[4];
    const float* eps   = (const float*)d_in[5];
    // d_in[6] = H unused: fast Walsh-Hadamard transform instead.

    float* outp = (float*)d_out;
    const int rows = out_size / WHVI_D;          // 8192
    whvi_main_kernel<<<rows / 8, 512, 0, stream>>>(x, s1, s2, g_mu, g_rho, eps, outp);
}